// Round 2
// baseline (2838.209 us; speedup 1.0000x reference)
//
#include <hip/hip_runtime.h>
#include <hip/hip_bf16.h>
#include <stdint.h>

#define B_    8
#define L_    8192
#define CIN   21
#define DM    512
#define DI    1024
#define DS    16
#define DTR   32
#define PRED  720
#define L0    (L_ - PRED)      /* 7472 */
#define NCH   16
#define CLEN  512

typedef __bf16 bf16_t;
typedef __attribute__((ext_vector_type(8))) __bf16 bf16x8;
typedef __attribute__((ext_vector_type(4))) float f32x4;

__device__ __forceinline__ void gl_lds16(const bf16_t* g, bf16_t* l) {
  __builtin_amdgcn_global_load_lds(
      (const __attribute__((address_space(1))) unsigned int*)g,
      (__attribute__((address_space(3))) unsigned int*)l, 16, 0, 0);
}

__device__ __forceinline__ float b2f(bf16_t v) { return (float)v; }
__device__ __forceinline__ bf16_t f2b(float v) { return (bf16_t)v; }

// ---------------- fallback: zero output (ws too small diagnostic) ----------------
__global__ void zero_kernel(float* __restrict__ out, int n) {
  int i = blockIdx.x * 256 + threadIdx.x;
  if (i < n) out[i] = 0.f;
}

// ---------------- RevIN stats: mean + stdev per (b, c) ----------------
__global__ __launch_bounds__(256) void stats_kernel(const float* __restrict__ x,
                                                    float* __restrict__ stats) {
  const int b = blockIdx.x / CIN, c = blockIdx.x % CIN;
  const int tid = threadIdx.x;
  float s = 0.f, s2 = 0.f;
  for (int l = tid; l < L_; l += 256) {
    float v = x[((size_t)b * L_ + l) * CIN + c];
    s += v; s2 += v * v;
  }
  __shared__ float rs[256], rs2[256];
  rs[tid] = s; rs2[tid] = s2;
  __syncthreads();
  for (int o = 128; o > 0; o >>= 1) {
    if (tid < o) { rs[tid] += rs[tid + o]; rs2[tid] += rs2[tid + o]; }
    __syncthreads();
  }
  if (tid == 0) {
    float mean = rs[0] / (float)L_;
    float var  = rs2[0] / (float)L_ - mean * mean;
    stats[(b * CIN + c) * 2]     = mean;
    stats[(b * CIN + c) * 2 + 1] = sqrtf(var + 1e-5f);
  }
}

// ---------------- transpose + f32->bf16 weight convert ----------------
__global__ void tconv_kernel(const float* __restrict__ in, bf16_t* __restrict__ out,
                             int R, int C) {
  int idx = blockIdx.x * 256 + threadIdx.x;
  if (idx < R * C) {
    int r = idx / C, c = idx % C;
    out[(size_t)c * R + r] = f2b(in[idx]);
  }
}

// ---------------- embedding (one batch): xn @ W_embed + b (K=21) ----------------
__global__ __launch_bounds__(512) void embed_kernel(const float* __restrict__ xb,
                                                    const float* __restrict__ stats_b,
                                                    const float* __restrict__ W,
                                                    const float* __restrict__ bias,
                                                    bf16_t* __restrict__ emb) {
  const int row = blockIdx.x;            // l in [0, 8192)
  __shared__ float xn[CIN];
  const int t = threadIdx.x;
  if (t < CIN) {
    float m = stats_b[t * 2], sd = stats_b[t * 2 + 1];
    xn[t] = (xb[(size_t)row * CIN + t] - m) / sd;
  }
  __syncthreads();
  float a = bias[t];
#pragma unroll
  for (int c = 0; c < CIN; ++c) a = fmaf(xn[c], W[c * DM + t], a);
  emb[(size_t)row * DM + t] = f2b(a);
}

// ---------------- generic bf16 MFMA GEMM, C = A(MxK) @ Bt(NxK)^T ----------------
// Per-batch row space (M = 8192 = l) except EPI 0.
// EPI 0: bf16 -> O1 (ld N)
// EPI 1: col<DI -> u raw (O1, ld DI); col>=DI && row>=L0 -> z (O1b, row-L0, ld DI)
// EPI 2: f32 -> Of (ld 64); col<DTR also bf16 -> O1b (ld DTR)
// EPI 3: softplus(acc + bias[col]) -> bf16 O1 (ld N)
template <int BM, int BN, int WNR, int EPI>
__global__ __launch_bounds__(256) void gemm_kernel(
    const bf16_t* __restrict__ A, const bf16_t* __restrict__ Bt,
    bf16_t* __restrict__ O1, bf16_t* __restrict__ O1b, float* __restrict__ Of,
    const float* __restrict__ bias, int M, int N, int K) {
  constexpr int WMR = 4;
  __shared__ bf16_t Alds[BM][32];
  __shared__ bf16_t Blds[BN][32];
  const int tid = threadIdx.x;
  const int wave = tid >> 6, lane = tid & 63;
  const int wm = wave >> 1, wn = wave & 1;
  const int lr = lane & 15, lk = lane >> 4;
  const int tm = blockIdx.x * BM;
  const int tn = blockIdx.y * BN;
  const int ldr = lane >> 2;            // row within a 16-row stage
  const int ldc = (lane & 3) * 8;       // bf16 element offset within row

  f32x4 acc[WMR][WNR] = {};

  const int nk = K >> 5;
  for (int ks = 0; ks < nk; ++ks) {
#pragma unroll
    for (int r = 0; r < BM / 64; ++r) {
      int row = r * 64 + wave * 16 + ldr;
      gl_lds16(A + (size_t)(tm + row) * K + ks * 32 + ldc, &Alds[r * 64 + wave * 16][0]);
    }
#pragma unroll
    for (int r = 0; r < BN / 64; ++r) {
      int row = r * 64 + wave * 16 + ldr;
      gl_lds16(Bt + (size_t)(tn + row) * K + ks * 32 + ldc, &Blds[r * 64 + wave * 16][0]);
    }
    __syncthreads();
    bf16x8 af[WMR], bfr[WNR];
#pragma unroll
    for (int mi = 0; mi < WMR; ++mi)
      af[mi] = *(const bf16x8*)(&Alds[wm * (WMR * 16) + mi * 16 + lr][lk * 8]);
#pragma unroll
    for (int ni = 0; ni < WNR; ++ni)
      bfr[ni] = *(const bf16x8*)(&Blds[wn * (WNR * 16) + ni * 16 + lr][lk * 8]);
#pragma unroll
    for (int mi = 0; mi < WMR; ++mi)
#pragma unroll
      for (int ni = 0; ni < WNR; ++ni)
        acc[mi][ni] = __builtin_amdgcn_mfma_f32_16x16x32_bf16(af[mi], bfr[ni], acc[mi][ni], 0, 0, 0);
    __syncthreads();
  }

#pragma unroll
  for (int mi = 0; mi < WMR; ++mi) {
#pragma unroll
    for (int ni = 0; ni < WNR; ++ni) {
#pragma unroll
      for (int r = 0; r < 4; ++r) {
        int row = tm + wm * (WMR * 16) + mi * 16 + lk * 4 + r;
        int col = tn + wn * (WNR * 16) + ni * 16 + lr;
        float v = acc[mi][ni][r];
        if constexpr (EPI == 0) {
          O1[(size_t)row * N + col] = f2b(v);
        } else if constexpr (EPI == 1) {
          if (col < DI) O1[(size_t)row * DI + col] = f2b(v);
          else if (row >= L0) O1b[(size_t)(row - L0) * DI + (col - DI)] = f2b(v);
        } else if constexpr (EPI == 2) {
          Of[(size_t)row * 64 + col] = v;
          if (col < DTR) O1b[(size_t)row * DTR + col] = f2b(v);
        } else if constexpr (EPI == 3) {
          float xx = v + bias[col];
          float sp = (xx > 20.f) ? xx : log1pf(__expf(xx));
          O1[(size_t)row * N + col] = f2b(sp);
        }
      }
    }
  }
}

// ---------------- causal depthwise conv (w=4) + bias + SiLU (one batch) ----------------
__global__ __launch_bounds__(256) void conv_kernel(const bf16_t* __restrict__ u_lin,
                                                   const float* __restrict__ cw,
                                                   const float* __restrict__ cb,
                                                   bf16_t* __restrict__ u_act) {
  const int tid = threadIdx.x;
  const int d = ((blockIdx.x & 3) << 8) + tid;
  const int row = blockIdx.x >> 2;       // l in [0, 8192)
  const float4 w = reinterpret_cast<const float4*>(cw)[d];
  const size_t base = (size_t)row * DI + d;
  float a = cb[d] + w.w * b2f(u_lin[base]);
  if (row >= 1) a += w.z * b2f(u_lin[base - DI]);
  if (row >= 2) a += w.y * b2f(u_lin[base - 2 * DI]);
  if (row >= 3) a += w.x * b2f(u_lin[base - 3 * DI]);
  float s = a / (1.f + __expf(-a));
  u_act[base] = f2b(s);
}

// ---------------- scan pass A (one batch): per-chunk partial states (h0 = 0) ----------------
__global__ __launch_bounds__(256) void scanA_kernel(
    const bf16_t* __restrict__ delta, const bf16_t* __restrict__ u_act,
    const float* __restrict__ xdbl, const float* __restrict__ A_log,
    float* __restrict__ q, float* __restrict__ Pm) {
  __shared__ float dl_s[16][16], uu_s[16][16], Bv_s[16][17];
  const int tid = threadIdx.x;
  const int bx = blockIdx.x;             // chunk*64 + dblk
  const int chunk = bx >> 6, dblk = bx & 63;
  const int g = tid >> 4, s = tid & 15;
  const int d = (dblk << 4) + g;
  const float As = __expf(A_log[d * DS + s]);   // = s+1
  float h = 0.f, dsum = 0.f;
  const int row0 = chunk * CLEN;
  for (int t16 = 0; t16 < CLEN / 16; ++t16) {
    __syncthreads();
    {
      int row = row0 + t16 * 16 + g;
      int dg = (dblk << 4) + s;
      dl_s[g][s] = b2f(delta[(size_t)row * DI + dg]);
      uu_s[g][s] = b2f(u_act[(size_t)row * DI + dg]);
      Bv_s[g][s] = xdbl[(size_t)row * 64 + 32 + s];
    }
    __syncthreads();
#pragma unroll
    for (int t = 0; t < 16; ++t) {
      float dlt = dl_s[t][g];
      float uu  = uu_s[t][g];
      float Bv  = Bv_s[t][s];
      float p = __expf(-dlt * As);
      h = fmaf(p, h, dlt * uu * Bv);
      dsum += dlt;
    }
  }
  const int off = d * 256 + chunk * 16 + s;
  q[off]  = h;
  Pm[off] = __expf(-dsum * As);
}

// ---------------- scan pass B (one batch): combine chunks ----------------
__global__ __launch_bounds__(256) void scanB_kernel(const float* __restrict__ q,
                                                    const float* __restrict__ Pm,
                                                    float* __restrict__ h0) {
  const int idx = blockIdx.x * 256 + threadIdx.x;   // 0..16383
  const int d = idx >> 4, s = idx & 15;
  float h = 0.f;
#pragma unroll
  for (int c = 0; c < NCH; ++c) {
    int off = d * 256 + c * 16 + s;
    h0[off] = h;
    h = fmaf(Pm[off], h, q[off]);
  }
}

// ---------------- scan pass C (one batch): re-scan last 2 chunks, gated y ----------------
__global__ __launch_bounds__(256) void scanC_kernel(
    const bf16_t* __restrict__ delta, const bf16_t* __restrict__ u_act,
    const float* __restrict__ xdbl, const float* __restrict__ A_log,
    const float* __restrict__ Dvec, const bf16_t* __restrict__ zbuf,
    const float* __restrict__ h0, bf16_t* __restrict__ yg) {
  __shared__ float dl_s[16][16], uu_s[16][16], Bv_s[16][17], Cv_s[16][17], z_s[16][16];
  const int tid = threadIdx.x;
  const int bx = blockIdx.x;             // ci*64 + dblk
  const int ci = bx >> 6, dblk = bx & 63;
  const int chunk = 14 + ci;
  const int g = tid >> 4, s = tid & 15;
  const int d = (dblk << 4) + g;
  const float As = __expf(A_log[d * DS + s]);
  const float Dd = Dvec[d];
  float h = h0[d * 256 + chunk * 16 + s];
  for (int t16 = 0; t16 < CLEN / 16; ++t16) {
    __syncthreads();
    {
      int lofs = chunk * CLEN + t16 * 16 + g;
      int dg = (dblk << 4) + s;
      dl_s[g][s] = b2f(delta[(size_t)lofs * DI + dg]);
      uu_s[g][s] = b2f(u_act[(size_t)lofs * DI + dg]);
      Bv_s[g][s] = xdbl[(size_t)lofs * 64 + 32 + s];
      Cv_s[g][s] = xdbl[(size_t)lofs * 64 + 48 + s];
      z_s[g][s] = (lofs >= L0) ? b2f(zbuf[(size_t)(lofs - L0) * DI + dg]) : 0.f;
    }
    __syncthreads();
#pragma unroll
    for (int t = 0; t < 16; ++t) {
      int l = chunk * CLEN + t16 * 16 + t;
      float dlt = dl_s[t][g];
      float uu  = uu_s[t][g];
      float Bv  = Bv_s[t][s];
      float p = __expf(-dlt * As);
      h = fmaf(p, h, dlt * uu * Bv);
      if (l >= L0) {
        float part = h * Cv_s[t][s];
        part += __shfl_xor(part, 1, 16);
        part += __shfl_xor(part, 2, 16);
        part += __shfl_xor(part, 4, 16);
        part += __shfl_xor(part, 8, 16);
        if (s == 0) {
          float y = part + uu * Dd;
          float z = z_s[t][g];
          float gate = z / (1.f + __expf(-z));
          yg[(size_t)(l - L0) * DI + d] = f2b(y * gate);
        }
      }
    }
  }
}

// ---------------- final: y1 @ W_proj + b, rescale by RevIN stats ----------------
__global__ __launch_bounds__(64) void final_kernel(const bf16_t* __restrict__ y1,
                                                   const float* __restrict__ Wp,
                                                   const float* __restrict__ bp,
                                                   const float* __restrict__ stats,
                                                   float* __restrict__ out) {
  const int row = blockIdx.x;            // b*720 + t
  const int b = row / PRED;
  __shared__ float ys[DM];
  for (int i = threadIdx.x; i < DM; i += 64) ys[i] = b2f(y1[(size_t)row * DM + i]);
  __syncthreads();
  const int c = threadIdx.x;
  if (c < CIN) {
    float a = bp[c];
    for (int k = 0; k < DM; ++k) a = fmaf(ys[k], Wp[k * CIN + c], a);
    float mean = stats[(b * CIN + c) * 2], sd = stats[(b * CIN + c) * 2 + 1];
    out[(size_t)row * CIN + c] = fmaf(a, sd, mean);
  }
}

// ---------------- launch ----------------
extern "C" void kernel_launch(void* const* d_in, const int* in_sizes, int n_in,
                              void* d_out, int out_size, void* d_ws, size_t ws_size,
                              hipStream_t stream) {
  const float* x_enc   = (const float*)d_in[0];
  const float* W_embed = (const float*)d_in[4];
  const float* b_embed = (const float*)d_in[5];
  const float* W_in    = (const float*)d_in[6];
  const float* conv_w  = (const float*)d_in[7];
  const float* conv_b  = (const float*)d_in[8];
  const float* W_xproj = (const float*)d_in[9];
  const float* W_dt    = (const float*)d_in[10];
  const float* b_dt    = (const float*)d_in[11];
  const float* A_log   = (const float*)d_in[12];
  const float* Dvec    = (const float*)d_in[13];
  const float* W_out   = (const float*)d_in[14];
  const float* W_proj  = (const float*)d_in[15];
  const float* b_proj  = (const float*)d_in[16];
  float* out = (float*)d_out;
  char* ws = (char*)d_ws;

  // per-batch buffers (reused for b = 0..7) + small globals: ~83 MB total
  constexpr size_t SZ_EMB  = (size_t)L_ * DM * 2;          //  8 MiB
  constexpr size_t SZ_URAW = (size_t)L_ * DI * 2;          // 16 MiB
  constexpr size_t SZ_UACT = SZ_URAW;                      // 16 MiB
  constexpr size_t SZ_DELT = SZ_URAW;                      // 16 MiB
  constexpr size_t SZ_ZBUF = (size_t)PRED * DI * 2;        // 1.44 MiB
  constexpr size_t SZ_XDBL = (size_t)L_ * 64 * 4;          //  2 MiB
  constexpr size_t SZ_DTB  = (size_t)L_ * DTR * 2;         //  0.5 MiB
  constexpr size_t SZ_QP   = (size_t)DI * NCH * DS * 4;    //  1 MiB
  constexpr size_t SZ_YG   = (size_t)B_ * PRED * DI * 2;   // 11.25 MiB (global)
  constexpr size_t SZ_Y1   = (size_t)B_ * PRED * DM * 2;   //  5.6 MiB (global)
  constexpr size_t SZ_WTIN  = (size_t)2048 * 512 * 2;
  constexpr size_t SZ_WTXP  = (size_t)64 * 1024 * 2;
  constexpr size_t SZ_WTDT  = (size_t)1024 * 32 * 2;
  constexpr size_t SZ_WTOUT = (size_t)512 * 1024 * 2;
  constexpr size_t SZ_STAT  = (size_t)B_ * CIN * 2 * 4;

  size_t off = 0;
  bf16_t* emb_b   = (bf16_t*)(ws + off); off += SZ_EMB;
  bf16_t* u_raw_b = (bf16_t*)(ws + off); off += SZ_URAW;
  bf16_t* u_act_b = (bf16_t*)(ws + off); off += SZ_UACT;
  bf16_t* delta_b = (bf16_t*)(ws + off); off += SZ_DELT;
  bf16_t* zbuf_b  = (bf16_t*)(ws + off); off += SZ_ZBUF;
  float*  xdbl_b  = (float*)(ws + off);  off += SZ_XDBL;
  bf16_t* dtb_b   = (bf16_t*)(ws + off); off += SZ_DTB;
  float*  q_b     = (float*)(ws + off);  off += SZ_QP;
  float*  Pm_b    = (float*)(ws + off);  off += SZ_QP;
  float*  h0_b    = (float*)(ws + off);  off += SZ_QP;
  bf16_t* yg      = (bf16_t*)(ws + off); off += SZ_YG;
  bf16_t* y1      = (bf16_t*)(ws + off); off += SZ_Y1;
  bf16_t* Wt_in   = (bf16_t*)(ws + off); off += SZ_WTIN;
  bf16_t* Wt_xp   = (bf16_t*)(ws + off); off += SZ_WTXP;
  bf16_t* Wt_dt   = (bf16_t*)(ws + off); off += SZ_WTDT;
  bf16_t* Wt_out  = (bf16_t*)(ws + off); off += SZ_WTOUT;
  float*  stats   = (float*)(ws + off);  off += SZ_STAT;

  if (ws_size < off) {   // diagnostic fallback: clean numeric failure, not a fault
    zero_kernel<<<(out_size + 255) / 256, 256, 0, stream>>>(out, out_size);
    return;
  }

  // global prep
  stats_kernel<<<B_ * CIN, 256, 0, stream>>>(x_enc, stats);
  tconv_kernel<<<(512 * 2048 + 255) / 256, 256, 0, stream>>>(W_in,    Wt_in, 512, 2048);
  tconv_kernel<<<(1024 * 64 + 255) / 256, 256, 0, stream>>>(W_xproj, Wt_xp, 1024, 64);
  tconv_kernel<<<(32 * 1024 + 255) / 256, 256, 0, stream>>>(W_dt,    Wt_dt, 32, 1024);
  tconv_kernel<<<(1024 * 512 + 255) / 256, 256, 0, stream>>>(W_out,   Wt_out, 1024, 512);

  for (int b = 0; b < B_; ++b) {
    const float* xb   = x_enc + (size_t)b * L_ * CIN;
    const float* st_b = stats + (size_t)b * CIN * 2;
    bf16_t* yg_b = yg + (size_t)b * PRED * DI;
    embed_kernel<<<L_, 512, 0, stream>>>(xb, st_b, W_embed, b_embed, emb_b);
    gemm_kernel<128, 128, 4, 1><<<dim3(L_ / 128, 2048 / 128), 256, 0, stream>>>(
        emb_b, Wt_in, u_raw_b, zbuf_b, nullptr, nullptr, L_, 2048, 512);
    conv_kernel<<<L_ * 4, 256, 0, stream>>>(u_raw_b, conv_w, conv_b, u_act_b);
    gemm_kernel<128, 64, 2, 2><<<dim3(L_ / 128, 1), 256, 0, stream>>>(
        u_act_b, Wt_xp, nullptr, dtb_b, xdbl_b, nullptr, L_, 64, 1024);
    gemm_kernel<128, 128, 4, 3><<<dim3(L_ / 128, 1024 / 128), 256, 0, stream>>>(
        dtb_b, Wt_dt, delta_b, nullptr, nullptr, b_dt, L_, 1024, 32);
    scanA_kernel<<<NCH * 64, 256, 0, stream>>>(delta_b, u_act_b, xdbl_b, A_log, q_b, Pm_b);
    scanB_kernel<<<(DI * DS) / 256, 256, 0, stream>>>(q_b, Pm_b, h0_b);
    scanC_kernel<<<2 * 64, 256, 0, stream>>>(delta_b, u_act_b, xdbl_b, A_log, Dvec,
                                             zbuf_b, h0_b, yg_b);
  }

  gemm_kernel<128, 128, 4, 0><<<dim3((B_ * PRED) / 128, 512 / 128), 256, 0, stream>>>(
      yg, Wt_out, y1, nullptr, nullptr, nullptr, B_ * PRED, 512, 1024);
  final_kernel<<<B_ * PRED, 64, 0, stream>>>(y1, W_proj, b_proj, stats, out);
}